// Round 6
// baseline (607.405 us; speedup 1.0000x reference)
//
#include <hip/hip_runtime.h>

#define NROWS 262144
#define PLANE_B   8388608ull   // NROWS*32 bytes per 16-col bf16 plane
#define PLANE_US  4194304ull   // ushorts per plane
#define KS 168                 // W1P/W2P row stride in ushorts

// ws byte offsets
#define H_B    0ull                          // 9 planes = 75,497,472 B
#define W1P_B  75497472ull                   // 144*168 bf16 = 48384 B
#define W2P_B  75545856ull                   // 48384 B
#define B1P_B  75594240ull                   // 144 f32
#define G4_B   75594816ull                   // 64*4 f32
#define ZT_B   75595840ull                   // 256*4 f32
#define SUMS_B 75599936ull                   // 32 slots * 288 f32 = 36864 B

typedef short  short8 __attribute__((ext_vector_type(8)));
typedef float  f32x4  __attribute__((ext_vector_type(4)));

static __device__ __forceinline__ unsigned short f2bf(float f) {
    unsigned u = __float_as_uint(f);
    u = u + 0x7fffu + ((u >> 16) & 1u);   // RNE
    return (unsigned short)(u >> 16);
}
static __device__ __forceinline__ float bf2f(unsigned short h) {
    return __uint_as_float(((unsigned)h) << 16);
}

// ------------------------------------------------------------------
// k_prep: fold linear front-end into GEMM-ready tables.
//  blocks 0..143: W1P[j] = [W1v@lin4 |64| W1z |64| W1n |3| 0], W2P[j], b1p[j]
//  block 144: G4[o] = {Ga,Gb,Gc,g0};  block 145: ZT;  block 146: zero sums
// ------------------------------------------------------------------
__global__ __launch_bounds__(64) void k_prep(
    const float* __restrict__ conv_w, const float* __restrict__ conv_b,
    const float* __restrict__ lin3_w, const float* __restrict__ lin3_b,
    const float* __restrict__ lin4_w, const float* __restrict__ lin4_b,
    const float* __restrict__ kern,
    const float* __restrict__ w1, const float* __restrict__ b1,
    const float* __restrict__ w2,
    unsigned short* __restrict__ W1P, unsigned short* __restrict__ W2P,
    float* __restrict__ B1P, float* __restrict__ G4, float* __restrict__ ZT,
    float* __restrict__ sums)
{
    const int j = blockIdx.x;
    const int l = threadIdx.x;
    if (j < 144) {
        const bool jv = (j < 131);
        float acc = 0.0f;
        if (jv) {
            #pragma unroll 4
            for (int o = 0; o < 64; o++)
                acc += w1[j * 131 + 3 + o] * lin4_w[o * 64 + l];
        }
        W1P[j * KS + l]      = jv ? f2bf(acc) : (unsigned short)0;
        W1P[j * KS + 64 + l] = jv ? f2bf(w1[j * 131 + 67 + l]) : (unsigned short)0;
        if (l < 40) {
            float v = (jv && l < 3) ? w1[j * 131 + l] : 0.0f;
            W1P[j * KS + 128 + l] = f2bf(v);
        }
        W2P[j * KS + l]      = jv ? f2bf(w2[j * 131 + l]) : (unsigned short)0;
        W2P[j * KS + 64 + l] = (jv && (64 + l) < 131) ? f2bf(w2[j * 131 + 64 + l]) : (unsigned short)0;
        if (l < 40) {
            int k2 = 128 + l;
            W2P[j * KS + k2] = (jv && k2 < 131) ? f2bf(w2[j * 131 + k2]) : (unsigned short)0;
        }
        if (l == 0) {
            float bb = 0.0f;
            if (jv) {
                bb = b1[j];
                for (int o = 0; o < 64; o++) bb += w1[j * 131 + 3 + o] * lin4_b[o];
            }
            B1P[j] = bb;
        }
    } else if (j == 144) {
        float g0v = lin3_b[l], ga = 0.0f, gb = 0.0f, gc = 0.0f;
        #pragma unroll 4
        for (int i = 0; i < 32; i++) {
            float wv = lin3_w[l * 32 + i];
            ga  += wv * (conv_w[i * 6 + 0] + conv_w[i * 6 + 3]);
            gb  += wv * (conv_w[i * 6 + 1] + conv_w[i * 6 + 4]);
            gc  += wv * (conv_w[i * 6 + 2] + conv_w[i * 6 + 5]);
            g0v += wv * conv_b[i];
        }
        G4[l * 4 + 0] = ga; G4[l * 4 + 1] = gb; G4[l * 4 + 2] = gc; G4[l * 4 + 3] = g0v;
    } else if (j == 145) {
        #pragma unroll
        for (int p = 0; p < 4; p++) {
            int idx = l * 4 + p;
            float kx = kern[idx * 3 + 0], ky = kern[idx * 3 + 1], kz = kern[idx * 3 + 2];
            ZT[idx * 4 + 0] = 2.0f * kx;
            ZT[idx * 4 + 1] = 2.0f * ky;
            ZT[idx * 4 + 2] = 2.0f * kz;
            ZT[idx * 4 + 3] = -(kx * kx + ky * ky + kz * kz);
        }
    } else {
        #pragma unroll
        for (int q = 0; q < 144; q++) sums[q * 64 + l] = 0.0f;
    }
}

// ------------------------------------------------------------------
// k_F: fused front-end + GEMM1, no X staging. 256 thr = 4 waves,
//  wave tile = 32 rows. Thread (c15,kg) computes its A-frag elements
//  (cols ks*32+kg*8+e of rows base+mi*16+c15) directly from m,n.
// ------------------------------------------------------------------
__global__ __launch_bounds__(256, 4) void k_F(
    const float* __restrict__ corner, const float* __restrict__ normal,
    const unsigned short* __restrict__ W1P, const float* __restrict__ B1P,
    const float* __restrict__ G4, const float* __restrict__ ZT,
    unsigned short* __restrict__ H, float* __restrict__ sums)
{
    __shared__ unsigned short mini[4][32][20];   // 5120 B
    __shared__ float sl[288];

    const int tid  = threadIdx.x;
    const int wave = tid >> 6, lane = tid & 63;
    const int kg   = lane >> 4, c15 = lane & 15;
    const int rowbase = blockIdx.x * 128 + wave * 32;

    for (int i = tid; i < 288; i += 256) sl[i] = 0.0f;
    __syncthreads();

    // ---- per-thread rows (mi=0,1) ----
    const int r0 = rowbase + c15, r1 = rowbase + 16 + c15;
    const float* cp0 = corner + (size_t)r0 * 9;
    const float* cp1 = corner + (size_t)r1 * 9;
    const float m00 = (cp0[0] + cp0[3] + cp0[6]) * (1.0f / 3.0f);
    const float m01 = (cp0[1] + cp0[4] + cp0[7]) * (1.0f / 3.0f);
    const float m02 = (cp0[2] + cp0[5] + cp0[8]) * (1.0f / 3.0f);
    const float m10 = (cp1[0] + cp1[3] + cp1[6]) * (1.0f / 3.0f);
    const float m11 = (cp1[1] + cp1[4] + cp1[7]) * (1.0f / 3.0f);
    const float m12 = (cp1[2] + cp1[5] + cp1[8]) * (1.0f / 3.0f);
    const float n00 = normal[r0 * 3 + 0], n01 = normal[r0 * 3 + 1], n02 = normal[r0 * 3 + 2];
    const float n10 = normal[r1 * 3 + 0], n11 = normal[r1 * 3 + 1], n12 = normal[r1 * 3 + 2];
    const float nn0 = n00 * n00 + n01 * n01 + n02 * n02;
    const float nn1 = n10 * n10 + n11 * n11 + n12 * n12;

    short8 af[2][5];
    // ---- t chunks (ks 0,1): o = ks*32 + kg*8 + e ----
    #pragma unroll
    for (int ks = 0; ks < 2; ks++) {
        short8 p0, p1;
        #pragma unroll
        for (int e = 0; e < 8; e++) {
            const f32x4 g = *(const f32x4*)(G4 + (ks * 32 + kg * 8 + e) * 4);
            float u0 = g[3] + m00 * g[0] + m01 * g[1] + m02 * g[2];
            float u1 = g[3] + m10 * g[0] + m11 * g[1] + m12 * g[2];
            p0[e] = (short)f2bf(fmaxf(u0, 0.0f));
            p1[e] = (short)f2bf(fmaxf(u1, 0.0f));
        }
        af[0][ks] = p0; af[1][ks] = p1;
    }
    // ---- z chunks (ks 2,3): zi = (ks-2)*32 + kg*8 + e ----
    #pragma unroll
    for (int ks = 2; ks < 4; ks++) {
        short8 p0, p1;
        #pragma unroll
        for (int e = 0; e < 8; e++) {
            const int zi = (ks - 2) * 32 + kg * 8 + e;
            float a0 = 0.0f, a1 = 0.0f;
            #pragma unroll
            for (int lp = 0; lp < 4; lp++) {
                const f32x4 zt = *(const f32x4*)(ZT + (zi * 4 + lp) * 4);
                a0 += __expf(zt[3] + zt[0] * n00 + zt[1] * n01 + zt[2] * n02 - nn0);
                a1 += __expf(zt[3] + zt[0] * n10 + zt[1] * n11 + zt[2] * n12 - nn1);
            }
            p0[e] = (short)f2bf(a0 * 0.03125f);
            p1[e] = (short)f2bf(a1 * 0.03125f);
        }
        af[0][ks] = p0; af[1][ks] = p1;
    }
    // ---- normal chunk (ks 4): k = 128 + kg*8 + e ----
    {
        short8 p0 = {0,0,0,0,0,0,0,0}, p1 = {0,0,0,0,0,0,0,0};
        if (kg == 0) {
            p0[0] = (short)f2bf(n00); p0[1] = (short)f2bf(n01); p0[2] = (short)f2bf(n02);
            p1[0] = (short)f2bf(n10); p1[1] = (short)f2bf(n11); p1[2] = (short)f2bf(n12);
        }
        af[0][4] = p0; af[1][4] = p1;
    }

    // ---- GEMM1: H(32x144) per wave ----
    #pragma unroll 1
    for (int n = 0; n < 9; n++) {
        const int col = n * 16 + c15;
        const float bias = B1P[col];
        short8 bf[5];
        #pragma unroll
        for (int ks = 0; ks < 5; ks++)
            bf[ks] = *(const short8*)(W1P + (size_t)col * KS + ks * 32 + kg * 8);
        f32x4 acc0 = {bias, bias, bias, bias};
        f32x4 acc1 = {bias, bias, bias, bias};
        #pragma unroll
        for (int ks = 0; ks < 5; ks++) {
            acc0 = __builtin_amdgcn_mfma_f32_16x16x32_bf16(af[0][ks], bf[ks], acc0, 0, 0, 0);
            acc1 = __builtin_amdgcn_mfma_f32_16x16x32_bf16(af[1][ks], bf[ks], acc1, 0, 0, 0);
        }
        // BN partials
        float s1 = acc0[0] + acc0[1] + acc0[2] + acc0[3]
                 + acc1[0] + acc1[1] + acc1[2] + acc1[3];
        float s2 = acc0[0]*acc0[0] + acc0[1]*acc0[1] + acc0[2]*acc0[2] + acc0[3]*acc0[3]
                 + acc1[0]*acc1[0] + acc1[1]*acc1[1] + acc1[2]*acc1[2] + acc1[3]*acc1[3];
        s1 += __shfl_xor(s1, 16); s2 += __shfl_xor(s2, 16);
        s1 += __shfl_xor(s1, 32); s2 += __shfl_xor(s2, 32);
        if (lane < 16) { atomicAdd(&sl[col], s1); atomicAdd(&sl[144 + col], s2); }
        // intra-wave transpose (DS ops are wave-ordered; no block barrier)
        #pragma unroll
        for (int r = 0; r < 4; r++) {
            mini[wave][kg * 4 + r][c15]      = f2bf(acc0[r]);
            mini[wave][16 + kg * 4 + r][c15] = f2bf(acc1[r]);
        }
        asm volatile("s_waitcnt lgkmcnt(0)" ::: "memory");
        __builtin_amdgcn_sched_barrier(0);
        const int rr = lane >> 1, hh = lane & 1;
        const uint2* q = (const uint2*)&mini[wave][rr][hh * 8];
        uint2 q0 = q[0], q1 = q[1];
        *(uint4*)((char*)H + (size_t)n * PLANE_B + (size_t)(rowbase + rr) * 32 + hh * 16)
            = make_uint4(q0.x, q0.y, q1.x, q1.y);
    }

    __syncthreads();
    {
        float* d = sums + (blockIdx.x & 31) * 288;
        for (int i = tid; i < 288; i += 256) atomicAdd(&d[i], sl[i]);
    }
}

// ------------------------------------------------------------------
// k_B: out = relu(scale*H + shift) @ W2P^T + b2. W2P read from global
//  (L1/L2-resident, shared table); BN params per block in LDS.
// ------------------------------------------------------------------
__global__ __launch_bounds__(256, 4) void k_B(
    const unsigned short* __restrict__ H, const unsigned short* __restrict__ W2P,
    const float* __restrict__ sums,
    const float* __restrict__ bn_g, const float* __restrict__ bn_b,
    const float* __restrict__ b2, float* __restrict__ out)
{
    __shared__ __align__(16) float s_scale[160];
    __shared__ __align__(16) float s_shift[160];

    const int tid = threadIdx.x;
    if (tid < 160) {
        float sc = 0.0f, sh = 0.0f;
        if (tid < 131) {
            float s1 = 0.0f, s2 = 0.0f;
            #pragma unroll 4
            for (int s = 0; s < 32; s++) {
                s1 += sums[s * 288 + tid];
                s2 += sums[s * 288 + 144 + tid];
            }
            const float inv = 1.0f / (float)NROWS;
            float mean = s1 * inv;
            float var  = fmaxf(s2 * inv - mean * mean, 0.0f);
            sc = bn_g[tid] * rsqrtf(var + 1e-5f);
            sh = bn_b[tid] - mean * sc;
        }
        s_scale[tid] = sc; s_shift[tid] = sh;
    }
    __syncthreads();

    const int wave = tid >> 6, lane = tid & 63;
    const int kg   = lane >> 4, c15 = lane & 15;
    const int rwave = blockIdx.x * 256 + wave * 64;

    #pragma unroll 1
    for (int mp = 0; mp < 2; mp++) {
        short8 af[2][5];
        #pragma unroll
        for (int mi = 0; mi < 2; mi++) {
            int arow = rwave + mp * 32 + mi * 16 + c15;
            #pragma unroll
            for (int ks = 0; ks < 5; ks++) {
                short8 res = {0, 0, 0, 0, 0, 0, 0, 0};
                if (ks < 4 || kg < 2) {
                    int p = (ks < 4) ? (ks * 2 + (kg >> 1)) : 8;
                    short8 h8 = *(const short8*)(H + (size_t)p * PLANE_US +
                                                 (size_t)arow * 16 + (kg & 1) * 8);
                    int c0 = ks * 32 + kg * 8;
                    #pragma unroll
                    for (int e = 0; e < 8; e++) {
                        float hf = bf2f((unsigned short)h8[e]);
                        res[e] = (short)f2bf(fmaxf(hf * s_scale[c0 + e] + s_shift[c0 + e], 0.0f));
                    }
                }
                af[mi][ks] = res;
            }
        }
        #pragma unroll 1
        for (int n = 0; n < 9; n++) {
            const int col = n * 16 + c15;
            const float bias = (col < 131) ? b2[col] : 0.0f;
            short8 bf[5];
            #pragma unroll
            for (int ks = 0; ks < 5; ks++)
                bf[ks] = *(const short8*)(W2P + (size_t)col * KS + ks * 32 + kg * 8);
            f32x4 acc0 = {bias, bias, bias, bias};
            f32x4 acc1 = {bias, bias, bias, bias};
            #pragma unroll
            for (int ks = 0; ks < 5; ks++) {
                acc0 = __builtin_amdgcn_mfma_f32_16x16x32_bf16(af[0][ks], bf[ks], acc0, 0, 0, 0);
                acc1 = __builtin_amdgcn_mfma_f32_16x16x32_bf16(af[1][ks], bf[ks], acc1, 0, 0, 0);
            }
            if (col < 131) {
                #pragma unroll
                for (int r = 0; r < 4; r++) {
                    out[(size_t)(rwave + mp * 32 + kg * 4 + r) * 131 + col]      = acc0[r];
                    out[(size_t)(rwave + mp * 32 + 16 + kg * 4 + r) * 131 + col] = acc1[r];
                }
            }
        }
    }
}

extern "C" void kernel_launch(void* const* d_in, const int* in_sizes, int n_in,
                              void* d_out, int out_size, void* d_ws, size_t ws_size,
                              hipStream_t stream) {
    (void)in_sizes; (void)n_in; (void)out_size; (void)ws_size;
    const float* corner = (const float*)d_in[0];
    const float* normal = (const float*)d_in[1];
    const float* conv_w = (const float*)d_in[3];
    const float* conv_b = (const float*)d_in[4];
    const float* lin3_w = (const float*)d_in[5];
    const float* lin3_b = (const float*)d_in[6];
    const float* lin4_w = (const float*)d_in[7];
    const float* lin4_b = (const float*)d_in[8];
    const float* kern   = (const float*)d_in[9];
    const float* w1     = (const float*)d_in[10];
    const float* b1     = (const float*)d_in[11];
    const float* bn_g   = (const float*)d_in[12];
    const float* bn_b   = (const float*)d_in[13];
    const float* w2     = (const float*)d_in[14];
    const float* b2     = (const float*)d_in[15];

    char* wsb = (char*)d_ws;
    unsigned short* Hp  = (unsigned short*)(wsb + H_B);
    unsigned short* W1P = (unsigned short*)(wsb + W1P_B);
    unsigned short* W2P = (unsigned short*)(wsb + W2P_B);
    float* B1P  = (float*)(wsb + B1P_B);
    float* G4   = (float*)(wsb + G4_B);
    float* ZT   = (float*)(wsb + ZT_B);
    float* sums = (float*)(wsb + SUMS_B);
    float* outp = (float*)d_out;

    k_prep<<<147, 64, 0, stream>>>(conv_w, conv_b, lin3_w, lin3_b, lin4_w, lin4_b,
                                   kern, w1, b1, w2, W1P, W2P, B1P, G4, ZT, sums);
    k_F<<<NROWS / 128, 256, 0, stream>>>(corner, normal, W1P, B1P, G4, ZT, Hp, sums);
    k_B<<<NROWS / 256, 256, 0, stream>>>(Hp, W2P, sums, bn_g, bn_b, b2, outp);
}

// Round 7
// 412.163 us; speedup vs baseline: 1.4737x; 1.4737x over previous
//
#include <hip/hip_runtime.h>

#define NROWS 262144
#define PLANE_B   8388608ull   // NROWS*32 bytes per 16-col bf16 plane
#define PLANE_US  4194304ull   // ushorts per plane
#define KS 168                 // W1P/W2P row stride in ushorts

// ws byte offsets
#define H_B    0ull                          // 9 planes = 75,497,472 B
#define W1P_B  75497472ull                   // 144*168 bf16 = 48384 B
#define W2P_B  75545856ull                   // 48384 B
#define B1P_B  75594240ull                   // 144 f32
#define G4_B   75594816ull                   // 64*4 f32
#define ZT_B   75595840ull                   // 256*4 f32
#define SUMS_B 75599936ull                   // 32 slots * 288 f32 = 36864 B

typedef short  short8 __attribute__((ext_vector_type(8)));
typedef float  f32x4  __attribute__((ext_vector_type(4)));

static __device__ __forceinline__ unsigned short f2bf(float f) {
    unsigned u = __float_as_uint(f);
    u = u + 0x7fffu + ((u >> 16) & 1u);   // RNE
    return (unsigned short)(u >> 16);
}
static __device__ __forceinline__ float bf2f(unsigned short h) {
    return __uint_as_float(((unsigned)h) << 16);
}

// ------------------------------------------------------------------
// k_prep: fold linear front-end into GEMM-ready tables.
//  blocks 0..143: W1P[j] = [W1v@lin4 |64| W1z |64| W1n |3| 0], W2P[j], b1p[j]
//  block 144: G4[o] = {Ga,Gb,Gc,g0};  block 145: ZT;  block 146: zero sums
// ------------------------------------------------------------------
__global__ __launch_bounds__(64) void k_prep(
    const float* __restrict__ conv_w, const float* __restrict__ conv_b,
    const float* __restrict__ lin3_w, const float* __restrict__ lin3_b,
    const float* __restrict__ lin4_w, const float* __restrict__ lin4_b,
    const float* __restrict__ kern,
    const float* __restrict__ w1, const float* __restrict__ b1,
    const float* __restrict__ w2,
    unsigned short* __restrict__ W1P, unsigned short* __restrict__ W2P,
    float* __restrict__ B1P, float* __restrict__ G4, float* __restrict__ ZT,
    float* __restrict__ sums)
{
    const int j = blockIdx.x;
    const int l = threadIdx.x;
    if (j < 144) {
        const bool jv = (j < 131);
        float acc = 0.0f;
        if (jv) {
            #pragma unroll 4
            for (int o = 0; o < 64; o++)
                acc += w1[j * 131 + 3 + o] * lin4_w[o * 64 + l];
        }
        W1P[j * KS + l]      = jv ? f2bf(acc) : (unsigned short)0;
        W1P[j * KS + 64 + l] = jv ? f2bf(w1[j * 131 + 67 + l]) : (unsigned short)0;
        if (l < 40) {
            float v = (jv && l < 3) ? w1[j * 131 + l] : 0.0f;
            W1P[j * KS + 128 + l] = f2bf(v);
        }
        W2P[j * KS + l]      = jv ? f2bf(w2[j * 131 + l]) : (unsigned short)0;
        W2P[j * KS + 64 + l] = (jv && (64 + l) < 131) ? f2bf(w2[j * 131 + 64 + l]) : (unsigned short)0;
        if (l < 40) {
            int k2 = 128 + l;
            W2P[j * KS + k2] = (jv && k2 < 131) ? f2bf(w2[j * 131 + k2]) : (unsigned short)0;
        }
        if (l == 0) {
            float bb = 0.0f;
            if (jv) {
                bb = b1[j];
                for (int o = 0; o < 64; o++) bb += w1[j * 131 + 3 + o] * lin4_b[o];
            }
            B1P[j] = bb;
        }
    } else if (j == 144) {
        float g0v = lin3_b[l], ga = 0.0f, gb = 0.0f, gc = 0.0f;
        #pragma unroll 4
        for (int i = 0; i < 32; i++) {
            float wv = lin3_w[l * 32 + i];
            ga  += wv * (conv_w[i * 6 + 0] + conv_w[i * 6 + 3]);
            gb  += wv * (conv_w[i * 6 + 1] + conv_w[i * 6 + 4]);
            gc  += wv * (conv_w[i * 6 + 2] + conv_w[i * 6 + 5]);
            g0v += wv * conv_b[i];
        }
        G4[l * 4 + 0] = ga; G4[l * 4 + 1] = gb; G4[l * 4 + 2] = gc; G4[l * 4 + 3] = g0v;
    } else if (j == 145) {
        #pragma unroll
        for (int p = 0; p < 4; p++) {
            int idx = l * 4 + p;
            float kx = kern[idx * 3 + 0], ky = kern[idx * 3 + 1], kz = kern[idx * 3 + 2];
            ZT[idx * 4 + 0] = 2.0f * kx;
            ZT[idx * 4 + 1] = 2.0f * ky;
            ZT[idx * 4 + 2] = 2.0f * kz;
            ZT[idx * 4 + 3] = -(kx * kx + ky * ky + kz * kz);
        }
    } else {
        #pragma unroll
        for (int q = 0; q < 144; q++) sums[q * 64 + l] = 0.0f;
    }
}

// ------------------------------------------------------------------
// k_F: fused front-end + GEMM1, no X staging. 256 thr = 4 waves,
//  wave tile = 32 rows. Thread (c15,kg) computes its A-frag elements
//  directly from m,n. launch_bounds(256,2): VGPR cap 256 — live set
//  ~90 VGPRs must NOT spill (r6: (256,4) forced 64 VGPR + 600MB scratch).
// ------------------------------------------------------------------
__global__ __launch_bounds__(256, 2) void k_F(
    const float* __restrict__ corner, const float* __restrict__ normal,
    const unsigned short* __restrict__ W1P, const float* __restrict__ B1P,
    const float* __restrict__ G4, const float* __restrict__ ZT,
    unsigned short* __restrict__ H, float* __restrict__ sums)
{
    __shared__ unsigned short mini[4][32][20];   // 5120 B
    __shared__ float sl[288];

    const int tid  = threadIdx.x;
    const int wave = tid >> 6, lane = tid & 63;
    const int kg   = lane >> 4, c15 = lane & 15;
    const int rowbase = blockIdx.x * 128 + wave * 32;

    for (int i = tid; i < 288; i += 256) sl[i] = 0.0f;
    __syncthreads();

    // ---- per-thread rows (mi=0,1) ----
    const int r0 = rowbase + c15, r1 = rowbase + 16 + c15;
    const float* cp0 = corner + (size_t)r0 * 9;
    const float* cp1 = corner + (size_t)r1 * 9;
    const float m00 = (cp0[0] + cp0[3] + cp0[6]) * (1.0f / 3.0f);
    const float m01 = (cp0[1] + cp0[4] + cp0[7]) * (1.0f / 3.0f);
    const float m02 = (cp0[2] + cp0[5] + cp0[8]) * (1.0f / 3.0f);
    const float m10 = (cp1[0] + cp1[3] + cp1[6]) * (1.0f / 3.0f);
    const float m11 = (cp1[1] + cp1[4] + cp1[7]) * (1.0f / 3.0f);
    const float m12 = (cp1[2] + cp1[5] + cp1[8]) * (1.0f / 3.0f);
    const float n00 = normal[r0 * 3 + 0], n01 = normal[r0 * 3 + 1], n02 = normal[r0 * 3 + 2];
    const float n10 = normal[r1 * 3 + 0], n11 = normal[r1 * 3 + 1], n12 = normal[r1 * 3 + 2];
    const float nn0 = n00 * n00 + n01 * n01 + n02 * n02;
    const float nn1 = n10 * n10 + n11 * n11 + n12 * n12;

    short8 af[2][5];
    // ---- t chunks (ks 0,1): o = ks*32 + kg*8 + e ----
    #pragma unroll
    for (int ks = 0; ks < 2; ks++) {
        short8 p0, p1;
        #pragma unroll
        for (int e = 0; e < 8; e++) {
            const f32x4 g = *(const f32x4*)(G4 + (ks * 32 + kg * 8 + e) * 4);
            float u0 = g[3] + m00 * g[0] + m01 * g[1] + m02 * g[2];
            float u1 = g[3] + m10 * g[0] + m11 * g[1] + m12 * g[2];
            p0[e] = (short)f2bf(fmaxf(u0, 0.0f));
            p1[e] = (short)f2bf(fmaxf(u1, 0.0f));
        }
        af[0][ks] = p0; af[1][ks] = p1;
    }
    // ---- z chunks (ks 2,3): zi = (ks-2)*32 + kg*8 + e ----
    #pragma unroll
    for (int ks = 2; ks < 4; ks++) {
        short8 p0, p1;
        #pragma unroll
        for (int e = 0; e < 8; e++) {
            const int zi = (ks - 2) * 32 + kg * 8 + e;
            float a0 = 0.0f, a1 = 0.0f;
            #pragma unroll
            for (int lp = 0; lp < 4; lp++) {
                const f32x4 zt = *(const f32x4*)(ZT + (zi * 4 + lp) * 4);
                a0 += __expf(zt[3] + zt[0] * n00 + zt[1] * n01 + zt[2] * n02 - nn0);
                a1 += __expf(zt[3] + zt[0] * n10 + zt[1] * n11 + zt[2] * n12 - nn1);
            }
            p0[e] = (short)f2bf(a0 * 0.03125f);
            p1[e] = (short)f2bf(a1 * 0.03125f);
        }
        af[0][ks] = p0; af[1][ks] = p1;
    }
    // ---- normal chunk (ks 4): k = 128 + kg*8 + e ----
    {
        short8 p0 = {0,0,0,0,0,0,0,0}, p1 = {0,0,0,0,0,0,0,0};
        if (kg == 0) {
            p0[0] = (short)f2bf(n00); p0[1] = (short)f2bf(n01); p0[2] = (short)f2bf(n02);
            p1[0] = (short)f2bf(n10); p1[1] = (short)f2bf(n11); p1[2] = (short)f2bf(n12);
        }
        af[0][4] = p0; af[1][4] = p1;
    }

    // ---- GEMM1: H(32x144) per wave ----
    #pragma unroll 1
    for (int n = 0; n < 9; n++) {
        const int col = n * 16 + c15;
        const float bias = B1P[col];
        short8 bf[5];
        #pragma unroll
        for (int ks = 0; ks < 5; ks++)
            bf[ks] = *(const short8*)(W1P + (size_t)col * KS + ks * 32 + kg * 8);
        f32x4 acc0 = {bias, bias, bias, bias};
        f32x4 acc1 = {bias, bias, bias, bias};
        #pragma unroll
        for (int ks = 0; ks < 5; ks++) {
            acc0 = __builtin_amdgcn_mfma_f32_16x16x32_bf16(af[0][ks], bf[ks], acc0, 0, 0, 0);
            acc1 = __builtin_amdgcn_mfma_f32_16x16x32_bf16(af[1][ks], bf[ks], acc1, 0, 0, 0);
        }
        // BN partials
        float s1 = acc0[0] + acc0[1] + acc0[2] + acc0[3]
                 + acc1[0] + acc1[1] + acc1[2] + acc1[3];
        float s2 = acc0[0]*acc0[0] + acc0[1]*acc0[1] + acc0[2]*acc0[2] + acc0[3]*acc0[3]
                 + acc1[0]*acc1[0] + acc1[1]*acc1[1] + acc1[2]*acc1[2] + acc1[3]*acc1[3];
        s1 += __shfl_xor(s1, 16); s2 += __shfl_xor(s2, 16);
        s1 += __shfl_xor(s1, 32); s2 += __shfl_xor(s2, 32);
        if (lane < 16) { atomicAdd(&sl[col], s1); atomicAdd(&sl[144 + col], s2); }
        // intra-wave transpose (DS ops are wave-ordered; no block barrier)
        #pragma unroll
        for (int r = 0; r < 4; r++) {
            mini[wave][kg * 4 + r][c15]      = f2bf(acc0[r]);
            mini[wave][16 + kg * 4 + r][c15] = f2bf(acc1[r]);
        }
        asm volatile("s_waitcnt lgkmcnt(0)" ::: "memory");
        __builtin_amdgcn_sched_barrier(0);
        const int rr = lane >> 1, hh = lane & 1;
        const uint2* q = (const uint2*)&mini[wave][rr][hh * 8];
        uint2 q0 = q[0], q1 = q[1];
        *(uint4*)((char*)H + (size_t)n * PLANE_B + (size_t)(rowbase + rr) * 32 + hh * 16)
            = make_uint4(q0.x, q0.y, q1.x, q1.y);
    }

    __syncthreads();
    {
        float* d = sums + (blockIdx.x & 31) * 288;
        for (int i = tid; i < 288; i += 256) atomicAdd(&d[i], sl[i]);
    }
}

// ------------------------------------------------------------------
// k_B: out = relu(scale*H + shift) @ W2P^T + b2. W2P read from global
//  (L1/L2-resident, shared table); BN params per block in LDS.
//  launch_bounds(256,2): same no-spill reasoning as k_F.
// ------------------------------------------------------------------
__global__ __launch_bounds__(256, 2) void k_B(
    const unsigned short* __restrict__ H, const unsigned short* __restrict__ W2P,
    const float* __restrict__ sums,
    const float* __restrict__ bn_g, const float* __restrict__ bn_b,
    const float* __restrict__ b2, float* __restrict__ out)
{
    __shared__ __align__(16) float s_scale[160];
    __shared__ __align__(16) float s_shift[160];

    const int tid = threadIdx.x;
    if (tid < 160) {
        float sc = 0.0f, sh = 0.0f;
        if (tid < 131) {
            float s1 = 0.0f, s2 = 0.0f;
            #pragma unroll 4
            for (int s = 0; s < 32; s++) {
                s1 += sums[s * 288 + tid];
                s2 += sums[s * 288 + 144 + tid];
            }
            const float inv = 1.0f / (float)NROWS;
            float mean = s1 * inv;
            float var  = fmaxf(s2 * inv - mean * mean, 0.0f);
            sc = bn_g[tid] * rsqrtf(var + 1e-5f);
            sh = bn_b[tid] - mean * sc;
        }
        s_scale[tid] = sc; s_shift[tid] = sh;
    }
    __syncthreads();

    const int wave = tid >> 6, lane = tid & 63;
    const int kg   = lane >> 4, c15 = lane & 15;
    const int rwave = blockIdx.x * 256 + wave * 64;

    #pragma unroll 1
    for (int mp = 0; mp < 2; mp++) {
        short8 af[2][5];
        #pragma unroll
        for (int mi = 0; mi < 2; mi++) {
            int arow = rwave + mp * 32 + mi * 16 + c15;
            #pragma unroll
            for (int ks = 0; ks < 5; ks++) {
                short8 res = {0, 0, 0, 0, 0, 0, 0, 0};
                if (ks < 4 || kg < 2) {
                    int p = (ks < 4) ? (ks * 2 + (kg >> 1)) : 8;
                    short8 h8 = *(const short8*)(H + (size_t)p * PLANE_US +
                                                 (size_t)arow * 16 + (kg & 1) * 8);
                    int c0 = ks * 32 + kg * 8;
                    #pragma unroll
                    for (int e = 0; e < 8; e++) {
                        float hf = bf2f((unsigned short)h8[e]);
                        res[e] = (short)f2bf(fmaxf(hf * s_scale[c0 + e] + s_shift[c0 + e], 0.0f));
                    }
                }
                af[mi][ks] = res;
            }
        }
        #pragma unroll 1
        for (int n = 0; n < 9; n++) {
            const int col = n * 16 + c15;
            const float bias = (col < 131) ? b2[col] : 0.0f;
            short8 bf[5];
            #pragma unroll
            for (int ks = 0; ks < 5; ks++)
                bf[ks] = *(const short8*)(W2P + (size_t)col * KS + ks * 32 + kg * 8);
            f32x4 acc0 = {bias, bias, bias, bias};
            f32x4 acc1 = {bias, bias, bias, bias};
            #pragma unroll
            for (int ks = 0; ks < 5; ks++) {
                acc0 = __builtin_amdgcn_mfma_f32_16x16x32_bf16(af[0][ks], bf[ks], acc0, 0, 0, 0);
                acc1 = __builtin_amdgcn_mfma_f32_16x16x32_bf16(af[1][ks], bf[ks], acc1, 0, 0, 0);
            }
            if (col < 131) {
                #pragma unroll
                for (int r = 0; r < 4; r++) {
                    out[(size_t)(rwave + mp * 32 + kg * 4 + r) * 131 + col]      = acc0[r];
                    out[(size_t)(rwave + mp * 32 + 16 + kg * 4 + r) * 131 + col] = acc1[r];
                }
            }
        }
    }
}

extern "C" void kernel_launch(void* const* d_in, const int* in_sizes, int n_in,
                              void* d_out, int out_size, void* d_ws, size_t ws_size,
                              hipStream_t stream) {
    (void)in_sizes; (void)n_in; (void)out_size; (void)ws_size;
    const float* corner = (const float*)d_in[0];
    const float* normal = (const float*)d_in[1];
    const float* conv_w = (const float*)d_in[3];
    const float* conv_b = (const float*)d_in[4];
    const float* lin3_w = (const float*)d_in[5];
    const float* lin3_b = (const float*)d_in[6];
    const float* lin4_w = (const float*)d_in[7];
    const float* lin4_b = (const float*)d_in[8];
    const float* kern   = (const float*)d_in[9];
    const float* w1     = (const float*)d_in[10];
    const float* b1     = (const float*)d_in[11];
    const float* bn_g   = (const float*)d_in[12];
    const float* bn_b   = (const float*)d_in[13];
    const float* w2     = (const float*)d_in[14];
    const float* b2     = (const float*)d_in[15];

    char* wsb = (char*)d_ws;
    unsigned short* Hp  = (unsigned short*)(wsb + H_B);
    unsigned short* W1P = (unsigned short*)(wsb + W1P_B);
    unsigned short* W2P = (unsigned short*)(wsb + W2P_B);
    float* B1P  = (float*)(wsb + B1P_B);
    float* G4   = (float*)(wsb + G4_B);
    float* ZT   = (float*)(wsb + ZT_B);
    float* sums = (float*)(wsb + SUMS_B);
    float* outp = (float*)d_out;

    k_prep<<<147, 64, 0, stream>>>(conv_w, conv_b, lin3_w, lin3_b, lin4_w, lin4_b,
                                   kern, w1, b1, w2, W1P, W2P, B1P, G4, ZT, sums);
    k_F<<<NROWS / 128, 256, 0, stream>>>(corner, normal, W1P, B1P, G4, ZT, Hp, sums);
    k_B<<<NROWS / 256, 256, 0, stream>>>(Hp, W2P, sums, bn_g, bn_b, b2, outp);
}

// Round 8
// 351.861 us; speedup vs baseline: 1.7263x; 1.1714x over previous
//
#include <hip/hip_runtime.h>

#define NROWS 262144
#define PLANE_B   8388608ull   // NROWS*32 bytes per 16-col bf16 plane
#define PLANE_US  4194304ull   // ushorts per plane
#define KS 168                 // W1P/W2P row stride in ushorts

// ws byte offsets
#define H_B    0ull                          // 9 planes = 75,497,472 B
#define W1P_B  75497472ull                   // 144*168 bf16 = 48384 B
#define W2P_B  75545856ull                   // 48384 B
#define B1P_B  75594240ull                   // 144 f32
#define G4_B   75594816ull                   // 64*4 f32
#define ZT_B   75595840ull                   // 256*4 f32
#define SUMS_B 75599936ull                   // 32 slots * 288 f32 = 36864 B

typedef short  short8 __attribute__((ext_vector_type(8)));
typedef float  f32x4  __attribute__((ext_vector_type(4)));

static __device__ __forceinline__ unsigned short f2bf(float f) {
    unsigned u = __float_as_uint(f);
    u = u + 0x7fffu + ((u >> 16) & 1u);   // RNE
    return (unsigned short)(u >> 16);
}
static __device__ __forceinline__ float bf2f(unsigned short h) {
    return __uint_as_float(((unsigned)h) << 16);
}

// ------------------------------------------------------------------
// k_prep: fold linear front-end into GEMM-ready tables.
//  blocks 0..143: W1P[j] = [W1v@lin4 |64| W1z |64| W1n |3| 0], W2P[j], b1p[j]
//  block 144: G4[o] = {Ga,Gb,Gc,g0};  block 145: ZT;  block 146: zero sums
// ------------------------------------------------------------------
__global__ __launch_bounds__(64) void k_prep(
    const float* __restrict__ conv_w, const float* __restrict__ conv_b,
    const float* __restrict__ lin3_w, const float* __restrict__ lin3_b,
    const float* __restrict__ lin4_w, const float* __restrict__ lin4_b,
    const float* __restrict__ kern,
    const float* __restrict__ w1, const float* __restrict__ b1,
    const float* __restrict__ w2,
    unsigned short* __restrict__ W1P, unsigned short* __restrict__ W2P,
    float* __restrict__ B1P, float* __restrict__ G4, float* __restrict__ ZT,
    float* __restrict__ sums)
{
    const int j = blockIdx.x;
    const int l = threadIdx.x;
    if (j < 144) {
        const bool jv = (j < 131);
        float acc = 0.0f;
        if (jv) {
            #pragma unroll 4
            for (int o = 0; o < 64; o++)
                acc += w1[j * 131 + 3 + o] * lin4_w[o * 64 + l];
        }
        W1P[j * KS + l]      = jv ? f2bf(acc) : (unsigned short)0;
        W1P[j * KS + 64 + l] = jv ? f2bf(w1[j * 131 + 67 + l]) : (unsigned short)0;
        if (l < 40) {
            float v = (jv && l < 3) ? w1[j * 131 + l] : 0.0f;
            W1P[j * KS + 128 + l] = f2bf(v);
        }
        W2P[j * KS + l]      = jv ? f2bf(w2[j * 131 + l]) : (unsigned short)0;
        W2P[j * KS + 64 + l] = (jv && (64 + l) < 131) ? f2bf(w2[j * 131 + 64 + l]) : (unsigned short)0;
        if (l < 40) {
            int k2 = 128 + l;
            W2P[j * KS + k2] = (jv && k2 < 131) ? f2bf(w2[j * 131 + k2]) : (unsigned short)0;
        }
        if (l == 0) {
            float bb = 0.0f;
            if (jv) {
                bb = b1[j];
                for (int o = 0; o < 64; o++) bb += w1[j * 131 + 3 + o] * lin4_b[o];
            }
            B1P[j] = bb;
        }
    } else if (j == 144) {
        float g0v = lin3_b[l], ga = 0.0f, gb = 0.0f, gc = 0.0f;
        #pragma unroll 4
        for (int i = 0; i < 32; i++) {
            float wv = lin3_w[l * 32 + i];
            ga  += wv * (conv_w[i * 6 + 0] + conv_w[i * 6 + 3]);
            gb  += wv * (conv_w[i * 6 + 1] + conv_w[i * 6 + 4]);
            gc  += wv * (conv_w[i * 6 + 2] + conv_w[i * 6 + 5]);
            g0v += wv * conv_b[i];
        }
        G4[l * 4 + 0] = ga; G4[l * 4 + 1] = gb; G4[l * 4 + 2] = gc; G4[l * 4 + 3] = g0v;
    } else if (j == 145) {
        #pragma unroll
        for (int p = 0; p < 4; p++) {
            int idx = l * 4 + p;
            float kx = kern[idx * 3 + 0], ky = kern[idx * 3 + 1], kz = kern[idx * 3 + 2];
            ZT[idx * 4 + 0] = 2.0f * kx;
            ZT[idx * 4 + 1] = 2.0f * ky;
            ZT[idx * 4 + 2] = 2.0f * kz;
            ZT[idx * 4 + 3] = -(kx * kx + ky * ky + kz * kz);
        }
    } else {
        #pragma unroll
        for (int q = 0; q < 144; q++) sums[q * 64 + l] = 0.0f;
    }
}

// ------------------------------------------------------------------
// k_F: fused front-end + GEMM1, no X staging. 256 thr = 4 waves,
//  wave tile = 32 rows. Thread (c15,kg) computes its A-frag elements
//  directly from m,n. Plain launch_bounds(256): NO min-occupancy arg —
//  (256,4)->64 VGPR and (256,2)->128 VGPR both forced scratch spill
//  (r6: 678MB, r7: 316MB WRITE). Live set ~90 VGPR must stay in regs.
// ------------------------------------------------------------------
__global__ __launch_bounds__(256) void k_F(
    const float* __restrict__ corner, const float* __restrict__ normal,
    const unsigned short* __restrict__ W1P, const float* __restrict__ B1P,
    const float* __restrict__ G4, const float* __restrict__ ZT,
    unsigned short* __restrict__ H, float* __restrict__ sums)
{
    __shared__ unsigned short mini[4][32][20];   // 5120 B
    __shared__ float sl[288];

    const int tid  = threadIdx.x;
    const int wave = tid >> 6, lane = tid & 63;
    const int kg   = lane >> 4, c15 = lane & 15;
    const int rowbase = blockIdx.x * 128 + wave * 32;

    for (int i = tid; i < 288; i += 256) sl[i] = 0.0f;
    __syncthreads();

    // ---- per-thread rows (mi=0,1) ----
    const int r0 = rowbase + c15, r1 = rowbase + 16 + c15;
    const float* cp0 = corner + (size_t)r0 * 9;
    const float* cp1 = corner + (size_t)r1 * 9;
    const float m00 = (cp0[0] + cp0[3] + cp0[6]) * (1.0f / 3.0f);
    const float m01 = (cp0[1] + cp0[4] + cp0[7]) * (1.0f / 3.0f);
    const float m02 = (cp0[2] + cp0[5] + cp0[8]) * (1.0f / 3.0f);
    const float m10 = (cp1[0] + cp1[3] + cp1[6]) * (1.0f / 3.0f);
    const float m11 = (cp1[1] + cp1[4] + cp1[7]) * (1.0f / 3.0f);
    const float m12 = (cp1[2] + cp1[5] + cp1[8]) * (1.0f / 3.0f);
    const float n00 = normal[r0 * 3 + 0], n01 = normal[r0 * 3 + 1], n02 = normal[r0 * 3 + 2];
    const float n10 = normal[r1 * 3 + 0], n11 = normal[r1 * 3 + 1], n12 = normal[r1 * 3 + 2];
    const float nn0 = n00 * n00 + n01 * n01 + n02 * n02;
    const float nn1 = n10 * n10 + n11 * n11 + n12 * n12;

    short8 af[2][5];
    // ---- t chunks (ks 0,1): o = ks*32 + kg*8 + e ----
    #pragma unroll
    for (int ks = 0; ks < 2; ks++) {
        short8 p0, p1;
        #pragma unroll
        for (int e = 0; e < 8; e++) {
            const f32x4 g = *(const f32x4*)(G4 + (ks * 32 + kg * 8 + e) * 4);
            float u0 = g[3] + m00 * g[0] + m01 * g[1] + m02 * g[2];
            float u1 = g[3] + m10 * g[0] + m11 * g[1] + m12 * g[2];
            p0[e] = (short)f2bf(fmaxf(u0, 0.0f));
            p1[e] = (short)f2bf(fmaxf(u1, 0.0f));
        }
        af[0][ks] = p0; af[1][ks] = p1;
    }
    // ---- z chunks (ks 2,3): zi = (ks-2)*32 + kg*8 + e ----
    #pragma unroll
    for (int ks = 2; ks < 4; ks++) {
        short8 p0, p1;
        #pragma unroll
        for (int e = 0; e < 8; e++) {
            const int zi = (ks - 2) * 32 + kg * 8 + e;
            float a0 = 0.0f, a1 = 0.0f;
            #pragma unroll
            for (int lp = 0; lp < 4; lp++) {
                const f32x4 zt = *(const f32x4*)(ZT + (zi * 4 + lp) * 4);
                a0 += __expf(zt[3] + zt[0] * n00 + zt[1] * n01 + zt[2] * n02 - nn0);
                a1 += __expf(zt[3] + zt[0] * n10 + zt[1] * n11 + zt[2] * n12 - nn1);
            }
            p0[e] = (short)f2bf(a0 * 0.03125f);
            p1[e] = (short)f2bf(a1 * 0.03125f);
        }
        af[0][ks] = p0; af[1][ks] = p1;
    }
    // ---- normal chunk (ks 4): k = 128 + kg*8 + e ----
    {
        short8 p0 = {0,0,0,0,0,0,0,0}, p1 = {0,0,0,0,0,0,0,0};
        if (kg == 0) {
            p0[0] = (short)f2bf(n00); p0[1] = (short)f2bf(n01); p0[2] = (short)f2bf(n02);
            p1[0] = (short)f2bf(n10); p1[1] = (short)f2bf(n11); p1[2] = (short)f2bf(n12);
        }
        af[0][4] = p0; af[1][4] = p1;
    }

    // ---- GEMM1: H(32x144) per wave ----
    #pragma unroll 1
    for (int n = 0; n < 9; n++) {
        const int col = n * 16 + c15;
        const float bias = B1P[col];
        short8 bf[5];
        #pragma unroll
        for (int ks = 0; ks < 5; ks++)
            bf[ks] = *(const short8*)(W1P + (size_t)col * KS + ks * 32 + kg * 8);
        f32x4 acc0 = {bias, bias, bias, bias};
        f32x4 acc1 = {bias, bias, bias, bias};
        #pragma unroll
        for (int ks = 0; ks < 5; ks++) {
            acc0 = __builtin_amdgcn_mfma_f32_16x16x32_bf16(af[0][ks], bf[ks], acc0, 0, 0, 0);
            acc1 = __builtin_amdgcn_mfma_f32_16x16x32_bf16(af[1][ks], bf[ks], acc1, 0, 0, 0);
        }
        // BN partials
        float s1 = acc0[0] + acc0[1] + acc0[2] + acc0[3]
                 + acc1[0] + acc1[1] + acc1[2] + acc1[3];
        float s2 = acc0[0]*acc0[0] + acc0[1]*acc0[1] + acc0[2]*acc0[2] + acc0[3]*acc0[3]
                 + acc1[0]*acc1[0] + acc1[1]*acc1[1] + acc1[2]*acc1[2] + acc1[3]*acc1[3];
        s1 += __shfl_xor(s1, 16); s2 += __shfl_xor(s2, 16);
        s1 += __shfl_xor(s1, 32); s2 += __shfl_xor(s2, 32);
        if (lane < 16) { atomicAdd(&sl[col], s1); atomicAdd(&sl[144 + col], s2); }
        // intra-wave transpose (DS ops are wave-ordered; no block barrier)
        #pragma unroll
        for (int r = 0; r < 4; r++) {
            mini[wave][kg * 4 + r][c15]      = f2bf(acc0[r]);
            mini[wave][16 + kg * 4 + r][c15] = f2bf(acc1[r]);
        }
        asm volatile("s_waitcnt lgkmcnt(0)" ::: "memory");
        __builtin_amdgcn_sched_barrier(0);
        const int rr = lane >> 1, hh = lane & 1;
        const uint2* q = (const uint2*)&mini[wave][rr][hh * 8];
        uint2 q0 = q[0], q1 = q[1];
        *(uint4*)((char*)H + (size_t)n * PLANE_B + (size_t)(rowbase + rr) * 32 + hh * 16)
            = make_uint4(q0.x, q0.y, q1.x, q1.y);
    }

    __syncthreads();
    {
        float* d = sums + (blockIdx.x & 31) * 288;
        for (int i = tid; i < 288; i += 256) atomicAdd(&d[i], sl[i]);
    }
}

// ------------------------------------------------------------------
// k_B: out = relu(scale*H + shift) @ W2P^T + b2. W2P read from global
//  (L1/L2-resident, shared table); BN params per block in LDS.
//  Plain launch_bounds(256): same no-spill reasoning as k_F.
// ------------------------------------------------------------------
__global__ __launch_bounds__(256) void k_B(
    const unsigned short* __restrict__ H, const unsigned short* __restrict__ W2P,
    const float* __restrict__ sums,
    const float* __restrict__ bn_g, const float* __restrict__ bn_b,
    const float* __restrict__ b2, float* __restrict__ out)
{
    __shared__ __align__(16) float s_scale[160];
    __shared__ __align__(16) float s_shift[160];

    const int tid = threadIdx.x;
    if (tid < 160) {
        float sc = 0.0f, sh = 0.0f;
        if (tid < 131) {
            float s1 = 0.0f, s2 = 0.0f;
            #pragma unroll 4
            for (int s = 0; s < 32; s++) {
                s1 += sums[s * 288 + tid];
                s2 += sums[s * 288 + 144 + tid];
            }
            const float inv = 1.0f / (float)NROWS;
            float mean = s1 * inv;
            float var  = fmaxf(s2 * inv - mean * mean, 0.0f);
            sc = bn_g[tid] * rsqrtf(var + 1e-5f);
            sh = bn_b[tid] - mean * sc;
        }
        s_scale[tid] = sc; s_shift[tid] = sh;
    }
    __syncthreads();

    const int wave = tid >> 6, lane = tid & 63;
    const int kg   = lane >> 4, c15 = lane & 15;
    const int rwave = blockIdx.x * 256 + wave * 64;

    #pragma unroll 1
    for (int mp = 0; mp < 2; mp++) {
        short8 af[2][5];
        #pragma unroll
        for (int mi = 0; mi < 2; mi++) {
            int arow = rwave + mp * 32 + mi * 16 + c15;
            #pragma unroll
            for (int ks = 0; ks < 5; ks++) {
                short8 res = {0, 0, 0, 0, 0, 0, 0, 0};
                if (ks < 4 || kg < 2) {
                    int p = (ks < 4) ? (ks * 2 + (kg >> 1)) : 8;
                    short8 h8 = *(const short8*)(H + (size_t)p * PLANE_US +
                                                 (size_t)arow * 16 + (kg & 1) * 8);
                    int c0 = ks * 32 + kg * 8;
                    #pragma unroll
                    for (int e = 0; e < 8; e++) {
                        float hf = bf2f((unsigned short)h8[e]);
                        res[e] = (short)f2bf(fmaxf(hf * s_scale[c0 + e] + s_shift[c0 + e], 0.0f));
                    }
                }
                af[mi][ks] = res;
            }
        }
        #pragma unroll 1
        for (int n = 0; n < 9; n++) {
            const int col = n * 16 + c15;
            const float bias = (col < 131) ? b2[col] : 0.0f;
            short8 bf[5];
            #pragma unroll
            for (int ks = 0; ks < 5; ks++)
                bf[ks] = *(const short8*)(W2P + (size_t)col * KS + ks * 32 + kg * 8);
            f32x4 acc0 = {bias, bias, bias, bias};
            f32x4 acc1 = {bias, bias, bias, bias};
            #pragma unroll
            for (int ks = 0; ks < 5; ks++) {
                acc0 = __builtin_amdgcn_mfma_f32_16x16x32_bf16(af[0][ks], bf[ks], acc0, 0, 0, 0);
                acc1 = __builtin_amdgcn_mfma_f32_16x16x32_bf16(af[1][ks], bf[ks], acc1, 0, 0, 0);
            }
            if (col < 131) {
                #pragma unroll
                for (int r = 0; r < 4; r++) {
                    out[(size_t)(rwave + mp * 32 + kg * 4 + r) * 131 + col]      = acc0[r];
                    out[(size_t)(rwave + mp * 32 + 16 + kg * 4 + r) * 131 + col] = acc1[r];
                }
            }
        }
    }
}

extern "C" void kernel_launch(void* const* d_in, const int* in_sizes, int n_in,
                              void* d_out, int out_size, void* d_ws, size_t ws_size,
                              hipStream_t stream) {
    (void)in_sizes; (void)n_in; (void)out_size; (void)ws_size;
    const float* corner = (const float*)d_in[0];
    const float* normal = (const float*)d_in[1];
    const float* conv_w = (const float*)d_in[3];
    const float* conv_b = (const float*)d_in[4];
    const float* lin3_w = (const float*)d_in[5];
    const float* lin3_b = (const float*)d_in[6];
    const float* lin4_w = (const float*)d_in[7];
    const float* lin4_b = (const float*)d_in[8];
    const float* kern   = (const float*)d_in[9];
    const float* w1     = (const float*)d_in[10];
    const float* b1     = (const float*)d_in[11];
    const float* bn_g   = (const float*)d_in[12];
    const float* bn_b   = (const float*)d_in[13];
    const float* w2     = (const float*)d_in[14];
    const float* b2     = (const float*)d_in[15];

    char* wsb = (char*)d_ws;
    unsigned short* Hp  = (unsigned short*)(wsb + H_B);
    unsigned short* W1P = (unsigned short*)(wsb + W1P_B);
    unsigned short* W2P = (unsigned short*)(wsb + W2P_B);
    float* B1P  = (float*)(wsb + B1P_B);
    float* G4   = (float*)(wsb + G4_B);
    float* ZT   = (float*)(wsb + ZT_B);
    float* sums = (float*)(wsb + SUMS_B);
    float* outp = (float*)d_out;

    k_prep<<<147, 64, 0, stream>>>(conv_w, conv_b, lin3_w, lin3_b, lin4_w, lin4_b,
                                   kern, w1, b1, w2, W1P, W2P, B1P, G4, ZT, sums);
    k_F<<<NROWS / 128, 256, 0, stream>>>(corner, normal, W1P, B1P, G4, ZT, Hp, sums);
    k_B<<<NROWS / 256, 256, 0, stream>>>(Hp, W2P, sums, bn_g, bn_b, b2, outp);
}